// Round 1
// baseline (1433.153 us; speedup 1.0000x reference)
//
#include <hip/hip_runtime.h>
#include <hip/hip_bf16.h>
#include <cstdint>
#include <cstddef>

#define N_NODES 50000
#define N_EDGES 800000
#define FIN 512
#define HW_ 128
#define NCLS 16

// ---------------- CSR build (counting sort by row) ----------------
__global__ void k_hist(const int* __restrict__ idx, int* __restrict__ cnt) {
  int e = blockIdx.x * blockDim.x + threadIdx.x;
  if (e < N_EDGES) atomicAdd(&cnt[idx[e]], 1);
}

__global__ void k_scan(const int* __restrict__ cnt, int* __restrict__ rowptr) {
  __shared__ int sums[1024];
  const int n = N_NODES;
  int tid = threadIdx.x;
  int chunk = (n + 1023) >> 10;
  int start = tid * chunk;
  int end = start + chunk; if (end > n) end = n;
  int s = 0;
  for (int i = start; i < end; i++) s += cnt[i];
  sums[tid] = s;
  __syncthreads();
  if (tid == 0) {
    int run = 0;
    for (int i = 0; i < 1024; i++) { int t = sums[i]; sums[i] = run; run += t; }
  }
  __syncthreads();
  int off = sums[tid];
  for (int i = start; i < end; i++) { rowptr[i] = off; off += cnt[i]; }
  if (end == n) rowptr[n] = off;   // one-or-more identical writers: total == E
}

__global__ void k_scatter(const int* __restrict__ idx, const float* __restrict__ vals,
                          int* __restrict__ wcur, int* __restrict__ ecol,
                          float* __restrict__ evalv) {
  int e = blockIdx.x * blockDim.x + threadIdx.x;
  if (e < N_EDGES) {
    int r = idx[e];
    int c = idx[N_EDGES + e];
    int p = atomicAdd(&wcur[r], 1);
    ecol[p] = c;
    evalv[p] = vals[e];
  }
}

// ---------------- SpMM: one wave per row, 128 cols (2/lane) ----------------
__global__ __launch_bounds__(256) void spmm_csr(
    const int* __restrict__ rowptr, const int* __restrict__ ecol,
    const float* __restrict__ evalv,
    const float* __restrict__ in, int istride,
    float* __restrict__ out, int ostride) {
  int wave = (int)((blockIdx.x * (size_t)blockDim.x + threadIdx.x) >> 6);
  int lane = threadIdx.x & 63;
  if (wave >= N_NODES) return;
  int s = rowptr[wave], e = rowptr[wave + 1];
  float acc0 = 0.f, acc1 = 0.f;
  for (int i = s; i < e; i++) {
    int c = ecol[i];
    float v = evalv[i];
    const float* src = in + (size_t)c * istride;
    acc0 += v * src[lane];
    acc1 += v * src[lane + 64];
  }
  out[(size_t)wave * ostride + lane] = acc0;
  out[(size_t)wave * ostride + lane + 64] = acc1;
}

// ---------------- Tiled fp32 GEMM with 3-way column-block routing -----------
// C[M, 384] = act(A[M,K] @ Wcat + bias), Wcat[k][j] = W[j>>7][k][j&127]
// Output column block i (128 wide) is routed to outI with strideI.
template <bool RELU>
__global__ __launch_bounds__(256) void gemm_routed(
    const float* __restrict__ A, int M, int K,
    const float* __restrict__ W,      // [3][K][128]
    const float* __restrict__ bias,   // [384] or nullptr
    float* __restrict__ o0, int s0,
    float* __restrict__ o1, int s1,
    float* __restrict__ o2, int s2) {
  __shared__ float sA[64][17];  // [m][k], padded
  __shared__ float sW[16][64];  // [k][n]
  int tid = threadIdx.x;
  int m0 = blockIdx.x * 64;
  int n0 = blockIdx.y * 64;          // global col 0..383, 64-aligned
  int blk = n0 >> 7;
  int nloc = n0 & 127;               // 0 or 64 within the 128-block
  const float* Wb = W + (size_t)blk * K * 128;

  int tx = tid & 15, ty = tid >> 4;  // 16x16 threads, 4x4 micro-tile each
  float acc[4][4] = {{0.f}};

  for (int k0 = 0; k0 < K; k0 += 16) {
    {
      int kk = tid & 15;
      int mm = tid >> 4;
#pragma unroll
      for (int i = 0; i < 4; i++) {
        int m = m0 + mm + 16 * i;
        float v = (m < M) ? A[(size_t)m * K + k0 + kk] : 0.f;
        sA[mm + 16 * i][kk] = v;
      }
    }
    {
      int nn = tid & 63;
      int kq = tid >> 6;             // 0..3
#pragma unroll
      for (int i = 0; i < 4; i++) {
        int k = kq * 4 + i;
        sW[k][nn] = Wb[(size_t)(k0 + k) * 128 + nloc + nn];
      }
    }
    __syncthreads();
#pragma unroll
    for (int k = 0; k < 16; k++) {
      float a[4], b[4];
#pragma unroll
      for (int i = 0; i < 4; i++) a[i] = sA[ty * 4 + i][k];
#pragma unroll
      for (int j = 0; j < 4; j++) b[j] = sW[k][tx * 4 + j];
#pragma unroll
      for (int i = 0; i < 4; i++)
#pragma unroll
        for (int j = 0; j < 4; j++) acc[i][j] += a[i] * b[j];
    }
    __syncthreads();
  }

  float* optr; int os;
  if (blk == 0)      { optr = o0; os = s0; }
  else if (blk == 1) { optr = o1; os = s1; }
  else               { optr = o2; os = s2; }

#pragma unroll
  for (int i = 0; i < 4; i++) {
    int m = m0 + ty * 4 + i;
    if (m >= M) continue;
#pragma unroll
    for (int j = 0; j < 4; j++) {
      int colg = n0 + tx * 4 + j;    // global col for bias
      int c = colg & 127;            // col within block
      float v = acc[i][j];
      if (bias) v += bias[colg];
      if (RELU) v = fmaxf(v, 0.f);
      optr[(size_t)m * os + c] = v;
    }
  }
}

// ---------------- constc[c] = bf[c] + sum_{i,k} b2[i][k] * wf[i*128+k][c] ---
__global__ void k_const(const float* __restrict__ b2, const float* __restrict__ wf,
                        const float* __restrict__ bf, float* __restrict__ constc) {
  int c = threadIdx.x;
  if (c >= NCLS) return;
  float s = bf[c];
  for (int k = 0; k < 384; k++) s += b2[k] * wf[k * NCLS + c];
  constc[c] = s;
}

// ---------------- final: logits = concat(f0,f1,f2) @ wf + constc; log_softmax
__global__ __launch_bounds__(256) void k_final(
    const float* __restrict__ f0, const float* __restrict__ f1,
    const float* __restrict__ f2, const float* __restrict__ wf,
    const float* __restrict__ constc, float* __restrict__ out) {
  __shared__ float swf[384 * NCLS];
  int tid = threadIdx.x;
  for (int i = tid; i < 384 * NCLS; i += 256) swf[i] = wf[i];
  __syncthreads();
  int r = blockIdx.x * 16 + (tid >> 4);
  int c = tid & 15;
  if (r >= N_NODES) return;
  float l = constc[c];
  const float* p0 = f0 + (size_t)r * HW_;
  const float* p1 = f1 + (size_t)r * HW_;
  const float* p2 = f2 + (size_t)r * HW_;
  for (int k = 0; k < HW_; k++) l += p0[k] * swf[k * NCLS + c];
  for (int k = 0; k < HW_; k++) l += p1[k] * swf[(HW_ + k) * NCLS + c];
  for (int k = 0; k < HW_; k++) l += p2[k] * swf[(2 * HW_ + k) * NCLS + c];
  float m = l;
  for (int o = 8; o >= 1; o >>= 1) m = fmaxf(m, __shfl_xor(m, o, 16));
  float s = expf(l - m);
  for (int o = 8; o >= 1; o >>= 1) s += __shfl_xor(s, o, 16);
  out[(size_t)r * NCLS + c] = (l - m) - logf(s);
}

// ---------------- launch ----------------
extern "C" void kernel_launch(void* const* d_in, const int* in_sizes, int n_in,
                              void* d_out, int out_size, void* d_ws, size_t ws_size,
                              hipStream_t stream) {
  const float* x   = (const float*)d_in[0];
  const int*   adj = (const int*)d_in[1];
  const float* av  = (const float*)d_in[2];
  const float* w1  = (const float*)d_in[3];
  const float* b1  = (const float*)d_in[4];  // [3*128] == [384]
  const float* w2  = (const float*)d_in[5];
  const float* b2  = (const float*)d_in[6];  // [3*128]
  const float* wf  = (const float*)d_in[7];  // [384,16]
  const float* bf  = (const float*)d_in[8];  // [16]
  float* out = (float*)d_out;

  char* ws = (char*)d_ws;
  size_t off = 0;
  auto alloc = [&](size_t bytes) -> void* {
    off = (off + 255) & ~(size_t)255;
    void* p = ws + off;
    off += bytes;
    return p;
  };

  float* a1   = (float*)alloc((size_t)N_NODES * 384 * 4);
  float* A    = (float*)alloc((size_t)N_NODES * HW_ * 4);
  float* B    = (float*)alloc((size_t)N_NODES * HW_ * 4);
  float* Cb   = (float*)alloc((size_t)N_NODES * HW_ * 4);
  float* D    = (float*)alloc((size_t)N_NODES * HW_ * 4);
  int* rowptr = (int*)alloc((size_t)(N_NODES + 1) * 4);
  int* wcur   = (int*)alloc((size_t)N_NODES * 4);
  int* cnt    = (int*)alloc((size_t)N_NODES * 4);
  int* ecol   = (int*)alloc((size_t)N_EDGES * 4);
  float* ev   = (float*)alloc((size_t)N_EDGES * 4);
  float* cc   = (float*)alloc(64);

  // CSR build
  hipMemsetAsync(cnt, 0, (size_t)N_NODES * 4, stream);
  k_hist<<<(N_EDGES + 255) / 256, 256, 0, stream>>>(adj, cnt);
  k_scan<<<1, 1024, 0, stream>>>(cnt, rowptr);
  hipMemcpyAsync(wcur, rowptr, (size_t)N_NODES * 4, hipMemcpyDeviceToDevice, stream);
  k_scatter<<<(N_EDGES + 255) / 256, 256, 0, stream>>>(adj, av, wcur, ecol, ev);
  k_const<<<1, 64, 0, stream>>>(b2, wf, bf, cc);

  dim3 ggrid((N_NODES + 63) / 64, 6);
  int spmm_grid = (N_NODES + 3) / 4;  // one 64-lane wave per row, 4 rows/block

  // Upper: GEMM1 -> blk0 straight to a1, blk1 -> A (1 hop), blk2 -> B (2 hops)
  gemm_routed<true><<<ggrid, 256, 0, stream>>>(x, N_NODES, FIN, w1, b1,
                                               a1, 384, A, HW_, B, HW_);
  spmm_csr<<<spmm_grid, 256, 0, stream>>>(rowptr, ecol, ev, A, HW_, a1 + 128, 384);
  spmm_csr<<<spmm_grid, 256, 0, stream>>>(rowptr, ecol, ev, B, HW_, A, HW_);
  spmm_csr<<<spmm_grid, 256, 0, stream>>>(rowptr, ecol, ev, A, HW_, a1 + 256, 384);

  // Bottom: GEMM2 -> A (f0), B (1 hop -> D = f1), Cb (2 hops -> Cb = f2)
  gemm_routed<false><<<ggrid, 256, 0, stream>>>(a1, N_NODES, 384, w2, nullptr,
                                                A, HW_, B, HW_, Cb, HW_);
  spmm_csr<<<spmm_grid, 256, 0, stream>>>(rowptr, ecol, ev, B, HW_, D, HW_);
  spmm_csr<<<spmm_grid, 256, 0, stream>>>(rowptr, ecol, ev, Cb, HW_, B, HW_);
  spmm_csr<<<spmm_grid, 256, 0, stream>>>(rowptr, ecol, ev, B, HW_, Cb, HW_);

  // Final fused GEMM + log_softmax
  k_final<<<(N_NODES + 15) / 16, 256, 0, stream>>>(A, D, Cb, wf, cc, out);
}

// Round 2
// 783.508 us; speedup vs baseline: 1.8291x; 1.8291x over previous
//
#include <hip/hip_runtime.h>
#include <hip/hip_bf16.h>
#include <cstdint>
#include <cstddef>

#define N_NODES 50000
#define N_EDGES 800000
#define FIN 512
#define HW_ 128
#define NCLS 16

typedef __attribute__((ext_vector_type(4))) float floatx4;
typedef __attribute__((ext_vector_type(4))) int int4v;
typedef __bf16 bf16x8 __attribute__((ext_vector_type(8)));

// ---------------- CSR build (counting sort by row) ----------------
__global__ void k_hist(const int* __restrict__ idx, int* __restrict__ cnt) {
  int e = blockIdx.x * blockDim.x + threadIdx.x;
  if (e < N_EDGES) atomicAdd(&cnt[idx[e]], 1);
}

__global__ void k_scan(const int* __restrict__ cnt, int* __restrict__ rowptr) {
  __shared__ int sums[1024];
  const int n = N_NODES;
  int tid = threadIdx.x;
  int chunk = (n + 1023) >> 10;
  int start = tid * chunk;
  int end = start + chunk; if (end > n) end = n;
  int s = 0;
  for (int i = start; i < end; i++) s += cnt[i];
  sums[tid] = s;
  __syncthreads();
  if (tid == 0) {
    int run = 0;
    for (int i = 0; i < 1024; i++) { int t = sums[i]; sums[i] = run; run += t; }
  }
  __syncthreads();
  int off = sums[tid];
  for (int i = start; i < end; i++) { rowptr[i] = off; off += cnt[i]; }
  if (end == n) rowptr[n] = off;
}

__global__ void k_scatter(const int* __restrict__ idx, const float* __restrict__ vals,
                          int* __restrict__ wcur, int* __restrict__ ecol,
                          float* __restrict__ evalv) {
  int e = blockIdx.x * blockDim.x + threadIdx.x;
  if (e < N_EDGES) {
    int r = idx[e];
    int c = idx[N_EDGES + e];
    int p = atomicAdd(&wcur[r], 1);
    ecol[p] = c;
    evalv[p] = vals[e];
  }
}

// ---------------- weight transpose + bf16 convert: [3][K][128] -> [3][128][K]
__global__ void k_wt(const float* __restrict__ in, __bf16* __restrict__ out, int K) {
  int t = blockIdx.x * 256 + threadIdx.x;
  int tot = 3 * K * 128;
  if (t >= tot) return;
  int i = t / (K * 128);
  int r = t - i * K * 128;
  int k = r >> 7;
  int nn = r & 127;
  out[(size_t)i * 128 * K + (size_t)nn * K + k] = (__bf16)in[t];
}

// ---------------- SpMM: one wave per row; shfl-broadcast edges; 4x unroll ----
template <bool OBF>
__global__ __launch_bounds__(256) void spmm_csr(
    const int* __restrict__ rowptr, const int* __restrict__ ecol,
    const float* __restrict__ evalv,
    const float* __restrict__ in,
    void* __restrict__ outp, int ostride) {
  int row = (int)((blockIdx.x * (size_t)blockDim.x + threadIdx.x) >> 6);
  int lane = threadIdx.x & 63;
  if (row >= N_NODES) return;
  int s = rowptr[row], e = rowptr[row + 1];
  float a0 = 0.f, a1 = 0.f;
  for (int i = s; i < e; i += 64) {
    int take = e - i; if (take > 64) take = 64;
    int c = (lane < take) ? ecol[i + lane] : 0;
    float v = (lane < take) ? evalv[i + lane] : 0.f;
    int j = 0;
    for (; j + 4 <= take; j += 4) {
      int c0 = __shfl(c, j), c1 = __shfl(c, j + 1), c2 = __shfl(c, j + 2), c3 = __shfl(c, j + 3);
      float w0 = __shfl(v, j), w1 = __shfl(v, j + 1), w2 = __shfl(v, j + 2), w3 = __shfl(v, j + 3);
      float2 x0 = *(const float2*)(in + ((size_t)c0 << 7) + 2 * lane);
      float2 x1 = *(const float2*)(in + ((size_t)c1 << 7) + 2 * lane);
      float2 x2 = *(const float2*)(in + ((size_t)c2 << 7) + 2 * lane);
      float2 x3 = *(const float2*)(in + ((size_t)c3 << 7) + 2 * lane);
      a0 += w0 * x0.x + w1 * x1.x + w2 * x2.x + w3 * x3.x;
      a1 += w0 * x0.y + w1 * x1.y + w2 * x2.y + w3 * x3.y;
    }
    for (; j < take; j++) {
      int c0 = __shfl(c, j);
      float w0 = __shfl(v, j);
      float2 x0 = *(const float2*)(in + ((size_t)c0 << 7) + 2 * lane);
      a0 += w0 * x0.x;
      a1 += w0 * x0.y;
    }
  }
  if (OBF) {
    __bf16* o = (__bf16*)outp;
    o[(size_t)row * ostride + 2 * lane] = (__bf16)a0;
    o[(size_t)row * ostride + 2 * lane + 1] = (__bf16)a1;
  } else {
    float* o = (float*)outp;
    o[(size_t)row * ostride + 2 * lane] = a0;
    o[(size_t)row * ostride + 2 * lane + 1] = a1;
  }
}

// ---------------- MFMA bf16 GEMM, 128x128 tile, 3-way column-block routing ---
// C[M, 384] = act(A[M,K] @ W + bias). W given transposed: Bt[3][128][K] bf16.
// blockIdx.y = 128-col block; blk0 may be written bf16 (a1 buffer).
template <bool HASB, bool B0BF, bool AF32>
__global__ __launch_bounds__(256) void gemm_mfma(
    const void* __restrict__ Ap, int M, int K,
    const __bf16* __restrict__ Bt,
    const float* __restrict__ bias,
    void* __restrict__ out0, int s0,
    float* __restrict__ out1, int s1,
    float* __restrict__ out2, int s2) {
  // LDS tiles [128 rows][40 bf16] (pad 32->40: 80B rows keep 16B alignment and
  // spread b128 accesses evenly over bank-quads)
  __shared__ __align__(16) __bf16 sA[128 * 40];
  __shared__ __align__(16) __bf16 sB[128 * 40];
  int tid = threadIdx.x;
  int m0 = blockIdx.x * 128;
  int blk = blockIdx.y;
  const __bf16* Bblk = Bt + (size_t)blk * 128 * K;
  int wave = tid >> 6, lane = tid & 63;
  int wm = (wave & 1) * 64, wn = (wave >> 1) * 64;
  floatx4 acc[4][4] = {};

  // staging: 512 16B-chunks per tile, 2 per thread; chunk c -> row c/4, quarter c%4
  int ar0 = tid >> 2, ch0 = tid & 3;
  int ar1 = (tid + 256) >> 2, ch1 = (tid + 256) & 3;
  // fragment addressing
  int fm = lane & 15, fg = lane >> 4;

  for (int k0 = 0; k0 < K; k0 += 32) {
    int4v av0, av1, bv0, bv1;
    if (AF32) {
      const float* Af = (const float*)Ap;
      union { int4v i; __bf16 h[8]; } u0, u1;
      int g0 = m0 + ar0, g1 = m0 + ar1;
      floatx4 p0a = {}, p0b = {}, p1a = {}, p1b = {};
      if (g0 < M) {
        const float* p = Af + (size_t)g0 * K + k0 + ch0 * 8;
        p0a = *(const floatx4*)p; p0b = *(const floatx4*)(p + 4);
      }
      if (g1 < M) {
        const float* p = Af + (size_t)g1 * K + k0 + ch1 * 8;
        p1a = *(const floatx4*)p; p1b = *(const floatx4*)(p + 4);
      }
#pragma unroll
      for (int q = 0; q < 4; q++) { u0.h[q] = (__bf16)p0a[q]; u0.h[q + 4] = (__bf16)p0b[q]; }
#pragma unroll
      for (int q = 0; q < 4; q++) { u1.h[q] = (__bf16)p1a[q]; u1.h[q + 4] = (__bf16)p1b[q]; }
      av0 = u0.i; av1 = u1.i;
    } else {
      const __bf16* Ab = (const __bf16*)Ap;
      int g0 = m0 + ar0, g1 = m0 + ar1;
      int4v z = {0, 0, 0, 0};
      av0 = (g0 < M) ? *(const int4v*)(Ab + (size_t)g0 * K + k0 + ch0 * 8) : z;
      av1 = (g1 < M) ? *(const int4v*)(Ab + (size_t)g1 * K + k0 + ch1 * 8) : z;
    }
    bv0 = *(const int4v*)(Bblk + (size_t)ar0 * K + k0 + ch0 * 8);
    bv1 = *(const int4v*)(Bblk + (size_t)ar1 * K + k0 + ch1 * 8);

    __syncthreads();
    *(int4v*)(sA + ar0 * 40 + ch0 * 8) = av0;
    *(int4v*)(sA + ar1 * 40 + ch1 * 8) = av1;
    *(int4v*)(sB + ar0 * 40 + ch0 * 8) = bv0;
    *(int4v*)(sB + ar1 * 40 + ch1 * 8) = bv1;
    __syncthreads();

    bf16x8 af[4], bf[4];
#pragma unroll
    for (int mt = 0; mt < 4; mt++)
      af[mt] = *(const bf16x8*)(sA + (wm + mt * 16 + fm) * 40 + fg * 8);
#pragma unroll
    for (int nt = 0; nt < 4; nt++)
      bf[nt] = *(const bf16x8*)(sB + (wn + nt * 16 + fm) * 40 + fg * 8);
#pragma unroll
    for (int mt = 0; mt < 4; mt++)
#pragma unroll
      for (int nt = 0; nt < 4; nt++)
        acc[mt][nt] = __builtin_amdgcn_mfma_f32_16x16x32_bf16(af[mt], bf[nt], acc[mt][nt], 0, 0, 0);
  }

  // epilogue: C/D layout col=lane&15, row=quad*4+reg (m89-verified)
  int colb = lane & 15, rbase = (lane >> 4) << 2;
  if (blk == 0) {
#pragma unroll
    for (int mt = 0; mt < 4; mt++)
#pragma unroll
      for (int r = 0; r < 4; r++) {
        int gm = m0 + wm + mt * 16 + rbase + r;
        if (gm >= M) continue;
#pragma unroll
        for (int nt = 0; nt < 4; nt++) {
          int gc = wn + nt * 16 + colb;
          float vv = acc[mt][nt][r];
          if (HASB) { vv += bias[gc]; vv = fmaxf(vv, 0.f); }
          if (B0BF) ((__bf16*)out0)[(size_t)gm * s0 + gc] = (__bf16)vv;
          else      ((float*)out0)[(size_t)gm * s0 + gc] = vv;
        }
      }
  } else {
    float* o = (blk == 1) ? out1 : out2;
    int s = (blk == 1) ? s1 : s2;
    const float* bp = bias + blk * 128;
#pragma unroll
    for (int mt = 0; mt < 4; mt++)
#pragma unroll
      for (int r = 0; r < 4; r++) {
        int gm = m0 + wm + mt * 16 + rbase + r;
        if (gm >= M) continue;
#pragma unroll
        for (int nt = 0; nt < 4; nt++) {
          int gc = wn + nt * 16 + colb;
          float vv = acc[mt][nt][r];
          if (HASB) { vv += bp[gc]; vv = fmaxf(vv, 0.f); }
          o[(size_t)gm * s + gc] = vv;
        }
      }
  }
}

// ---------------- constc[c] = bf[c] + sum_k b2[k] * wf[k][c] ----------------
__global__ void k_const(const float* __restrict__ b2, const float* __restrict__ wf,
                        const float* __restrict__ bf, float* __restrict__ constc) {
  int c = threadIdx.x;
  if (c >= NCLS) return;
  float s = bf[c];
  for (int k = 0; k < 384; k++) s += b2[k] * wf[k * NCLS + c];
  constc[c] = s;
}

// ---------------- final: logits = concat(f0,f1,f2) @ wf + constc; log_softmax
__global__ __launch_bounds__(256) void k_final(
    const float* __restrict__ f0, const float* __restrict__ f1,
    const float* __restrict__ f2, const float* __restrict__ wf,
    const float* __restrict__ constc, float* __restrict__ out) {
  __shared__ float swf[384 * NCLS];
  int tid = threadIdx.x;
  for (int i = tid; i < 384 * NCLS; i += 256) swf[i] = wf[i];
  __syncthreads();
  int r = blockIdx.x * 16 + (tid >> 4);
  int c = tid & 15;
  if (r >= N_NODES) return;
  float l = constc[c];
  const float* p0 = f0 + (size_t)r * HW_;
  const float* p1 = f1 + (size_t)r * HW_;
  const float* p2 = f2 + (size_t)r * HW_;
  for (int k = 0; k < HW_; k++) l += p0[k] * swf[k * NCLS + c];
  for (int k = 0; k < HW_; k++) l += p1[k] * swf[(HW_ + k) * NCLS + c];
  for (int k = 0; k < HW_; k++) l += p2[k] * swf[(2 * HW_ + k) * NCLS + c];
  float m = l;
  for (int o = 8; o >= 1; o >>= 1) m = fmaxf(m, __shfl_xor(m, o, 16));
  float s = expf(l - m);
  for (int o = 8; o >= 1; o >>= 1) s += __shfl_xor(s, o, 16);
  out[(size_t)r * NCLS + c] = (l - m) - logf(s);
}

// ---------------- launch ----------------
extern "C" void kernel_launch(void* const* d_in, const int* in_sizes, int n_in,
                              void* d_out, int out_size, void* d_ws, size_t ws_size,
                              hipStream_t stream) {
  const float* x   = (const float*)d_in[0];
  const int*   adj = (const int*)d_in[1];
  const float* av  = (const float*)d_in[2];
  const float* w1  = (const float*)d_in[3];
  const float* b1  = (const float*)d_in[4];  // [384]
  const float* w2  = (const float*)d_in[5];
  const float* b2  = (const float*)d_in[6];  // [384]
  const float* wf  = (const float*)d_in[7];  // [384,16]
  const float* bf  = (const float*)d_in[8];  // [16]
  float* out = (float*)d_out;

  char* ws = (char*)d_ws;
  size_t off = 0;
  auto alloc = [&](size_t bytes) -> void* {
    off = (off + 255) & ~(size_t)255;
    void* p = ws + off;
    off += bytes;
    return p;
  };

  __bf16* a1b = (__bf16*)alloc((size_t)N_NODES * 384 * 2);
  float* A    = (float*)alloc((size_t)N_NODES * HW_ * 4);
  float* B    = (float*)alloc((size_t)N_NODES * HW_ * 4);
  float* C    = (float*)alloc((size_t)N_NODES * HW_ * 4);
  float* D    = (float*)alloc((size_t)N_NODES * HW_ * 4);
  __bf16* w1t = (__bf16*)alloc((size_t)3 * 128 * FIN * 2);
  __bf16* w2t = (__bf16*)alloc((size_t)3 * 128 * 384 * 2);
  int* rowptr = (int*)alloc((size_t)(N_NODES + 1) * 4);
  int* wcur   = (int*)alloc((size_t)N_NODES * 4);
  int* cnt    = (int*)alloc((size_t)N_NODES * 4);
  int* ecol   = (int*)alloc((size_t)N_EDGES * 4);
  float* ev   = (float*)alloc((size_t)N_EDGES * 4);
  float* cc   = (float*)alloc(64);

  // CSR build
  hipMemsetAsync(cnt, 0, (size_t)N_NODES * 4, stream);
  k_hist<<<(N_EDGES + 255) / 256, 256, 0, stream>>>(adj, cnt);
  k_scan<<<1, 1024, 0, stream>>>(cnt, rowptr);
  hipMemcpyAsync(wcur, rowptr, (size_t)N_NODES * 4, hipMemcpyDeviceToDevice, stream);
  k_scatter<<<(N_EDGES + 255) / 256, 256, 0, stream>>>(adj, av, wcur, ecol, ev);
  k_const<<<1, 64, 0, stream>>>(b2, wf, bf, cc);

  // weight transpose+convert
  k_wt<<<(3 * FIN * 128 + 255) / 256, 256, 0, stream>>>(w1, w1t, FIN);
  k_wt<<<(3 * 384 * 128 + 255) / 256, 256, 0, stream>>>(w2, w2t, 384);

  dim3 g1((N_NODES + 127) / 128, 3);
  int spmm_grid = (N_NODES + 3) / 4;

  // GEMM1: relu(x@w1+b1): blk0 -> a1b bf16 cols 0-127; blk1 -> A; blk2 -> B
  gemm_mfma<true, true, true><<<g1, 256, 0, stream>>>(
      (const void*)x, N_NODES, FIN, w1t, b1, (void*)a1b, 384, A, HW_, B, HW_);
  // hops (upper)
  spmm_csr<true><<<spmm_grid, 256, 0, stream>>>(rowptr, ecol, ev, A, (void*)(a1b + 128), 384);
  spmm_csr<false><<<spmm_grid, 256, 0, stream>>>(rowptr, ecol, ev, B, (void*)A, HW_);
  spmm_csr<true><<<spmm_grid, 256, 0, stream>>>(rowptr, ecol, ev, A, (void*)(a1b + 256), 384);

  // GEMM2: a1b@w2 (bias folded into constc): blk0 -> A (f0); blk1 -> B; blk2 -> C
  gemm_mfma<false, false, false><<<g1, 256, 0, stream>>>(
      (const void*)a1b, N_NODES, 384, w2t, nullptr, (void*)A, HW_, B, HW_, C, HW_);
  // hops (bottom)
  spmm_csr<false><<<spmm_grid, 256, 0, stream>>>(rowptr, ecol, ev, B, (void*)D, HW_);
  spmm_csr<false><<<spmm_grid, 256, 0, stream>>>(rowptr, ecol, ev, C, (void*)B, HW_);
  spmm_csr<false><<<spmm_grid, 256, 0, stream>>>(rowptr, ecol, ev, B, (void*)C, HW_);

  // final fused GEMM + log_softmax
  k_final<<<(N_NODES + 15) / 16, 256, 0, stream>>>(A, D, C, wf, cc, out);
}

// Round 3
// 583.249 us; speedup vs baseline: 2.4572x; 1.3433x over previous
//
#include <hip/hip_runtime.h>
#include <hip/hip_bf16.h>
#include <cstdint>
#include <cstddef>

#define N_NODES 50000
#define N_EDGES 800000
#define FIN 512
#define HW_ 128
#define NCLS 16
#define SCAN_NB 196  // ceil(50000/256)

typedef __attribute__((ext_vector_type(4))) float floatx4;
typedef __attribute__((ext_vector_type(4))) int int4v;
typedef __bf16 bf16x8 __attribute__((ext_vector_type(8)));
struct alignas(4) bh2 { __bf16 x, y; };

// ---------------- CSR build: histogram ----------------
__global__ void k_hist(const int* __restrict__ idx, int* __restrict__ cnt) {
  int e = blockIdx.x * blockDim.x + threadIdx.x;
  if (e < N_EDGES) atomicAdd(&cnt[idx[e]], 1);
}

// ---------------- parallel scan: per-block sums ----------------
__global__ __launch_bounds__(256) void k_scan_block(const int* __restrict__ cnt,
                                                    int* __restrict__ bsum) {
  int t = blockIdx.x * 256 + threadIdx.x;
  int v = (t < N_NODES) ? cnt[t] : 0;
#pragma unroll
  for (int o = 32; o >= 1; o >>= 1) v += __shfl_down(v, o);
  __shared__ int ws[4];
  if ((threadIdx.x & 63) == 0) ws[threadIdx.x >> 6] = v;
  __syncthreads();
  if (threadIdx.x == 0) bsum[blockIdx.x] = ws[0] + ws[1] + ws[2] + ws[3];
}

// ---------------- parallel scan: top-level exclusive scan of block sums -----
__global__ __launch_bounds__(256) void k_scan_top(const int* __restrict__ bsum,
                                                  int* __restrict__ bsumex) {
  int t = threadIdx.x;
  int lane = t & 63;
  int orig = (t < SCAN_NB) ? bsum[t] : 0;
  int v = orig;
#pragma unroll
  for (int o = 1; o < 64; o <<= 1) {
    int n = __shfl_up(v, o);
    if (lane >= o) v += n;
  }
  __shared__ int wt[4];
  if (lane == 63) wt[t >> 6] = v;
  __syncthreads();
  int add = 0;
  for (int w = 0; w < (t >> 6); w++) add += wt[w];
  if (t < SCAN_NB) bsumex[t] = v + add - orig;
}

// ---------------- parallel scan: fill rowptr + wcur ----------------
__global__ __launch_bounds__(256) void k_scan_fill(const int* __restrict__ cnt,
                                                   const int* __restrict__ bsumex,
                                                   int* __restrict__ rowptr,
                                                   int* __restrict__ wcur) {
  int t = blockIdx.x * 256 + threadIdx.x;
  int lane = threadIdx.x & 63;
  int c = (t < N_NODES) ? cnt[t] : 0;
  int v = c;
#pragma unroll
  for (int o = 1; o < 64; o <<= 1) {
    int n = __shfl_up(v, o);
    if (lane >= o) v += n;
  }
  __shared__ int wt[4];
  if (lane == 63) wt[threadIdx.x >> 6] = v;
  __syncthreads();
  int add = bsumex[blockIdx.x];
  for (int w = 0; w < (threadIdx.x >> 6); w++) add += wt[w];
  int ex = v - c + add;
  if (t < N_NODES) { rowptr[t] = ex; wcur[t] = ex; }
  if (t == 0) rowptr[N_NODES] = N_EDGES;
}

// ---------------- scatter edges (packed col+val) ----------------
__global__ void k_scatter(const int* __restrict__ idx, const float* __restrict__ vals,
                          int* __restrict__ wcur, int2* __restrict__ epack) {
  int e = blockIdx.x * blockDim.x + threadIdx.x;
  if (e < N_EDGES) {
    int r = idx[e];
    int c = idx[N_EDGES + e];
    int p = atomicAdd(&wcur[r], 1);
    epack[p] = make_int2(c, __float_as_int(vals[e]));
  }
}

// ---------------- weight transpose + bf16 convert: [3][K][128] -> [3][128][K]
__global__ void k_wt(const float* __restrict__ in, __bf16* __restrict__ out, int K) {
  int t = blockIdx.x * 256 + threadIdx.x;
  int tot = 3 * K * 128;
  if (t >= tot) return;
  int i = t / (K * 128);
  int r = t - i * K * 128;
  int k = r >> 7;
  int nn = r & 127;
  out[(size_t)i * 128 * K + (size_t)nn * K + k] = (__bf16)in[t];
}

// ---------------- SpMM: one wave/row, bf16 gather rows, shfl-broadcast edges
template <bool OUTF32>
__global__ __launch_bounds__(256) void spmm_csr(
    const int* __restrict__ rowptr, const int2* __restrict__ epack,
    const __bf16* __restrict__ in,
    void* __restrict__ outp, int ostride) {
  int row = (int)((blockIdx.x * (size_t)blockDim.x + threadIdx.x) >> 6);
  int lane = threadIdx.x & 63;
  if (row >= N_NODES) return;
  int s = rowptr[row], e = rowptr[row + 1];
  float a0 = 0.f, a1 = 0.f;
  for (int i = s; i < e; i += 64) {
    int take = e - i; if (take > 64) take = 64;
    int2 ed = (lane < take) ? epack[i + lane] : make_int2(0, 0);
    int c = ed.x;
    float v = __int_as_float(ed.y);
    int j = 0;
    for (; j + 8 <= take; j += 8) {
      int cc[8]; float ww[8]; bh2 p[8];
#pragma unroll
      for (int u = 0; u < 8; u++) { cc[u] = __shfl(c, j + u); ww[u] = __shfl(v, j + u); }
#pragma unroll
      for (int u = 0; u < 8; u++) p[u] = *(const bh2*)(in + ((size_t)cc[u] << 7) + 2 * lane);
#pragma unroll
      for (int u = 0; u < 8; u++) {
        a0 += ww[u] * (float)p[u].x;
        a1 += ww[u] * (float)p[u].y;
      }
    }
    for (; j < take; j++) {
      int c0 = __shfl(c, j);
      float w0 = __shfl(v, j);
      bh2 p = *(const bh2*)(in + ((size_t)c0 << 7) + 2 * lane);
      a0 += w0 * (float)p.x;
      a1 += w0 * (float)p.y;
    }
  }
  if (OUTF32) {
    float2* o = (float2*)((float*)outp + (size_t)row * ostride + 2 * lane);
    *o = make_float2(a0, a1);
  } else {
    bh2* o = (bh2*)((__bf16*)outp + (size_t)row * ostride + 2 * lane);
    bh2 w; w.x = (__bf16)a0; w.y = (__bf16)a1;
    *o = w;
  }
}

// ---------------- MFMA bf16 GEMM, 128x128 tile, 3-way column-block routing ---
// C[M,384] = act(A[M,K] @ W + bias). W transposed: Bt[3][128][K] bf16.
// out0 dtype per O0F32; out1/out2 always bf16.
template <bool HASB, bool AF32, bool O0F32>
__global__ __launch_bounds__(256) void gemm_mfma(
    const void* __restrict__ Ap, int M, int K,
    const __bf16* __restrict__ Bt,
    const float* __restrict__ bias,
    void* __restrict__ out0, int s0,
    __bf16* __restrict__ out1, int s1,
    __bf16* __restrict__ out2, int s2) {
  __shared__ __align__(16) __bf16 sA[128 * 40];
  __shared__ __align__(16) __bf16 sB[128 * 40];
  int tid = threadIdx.x;
  int m0 = blockIdx.x * 128;
  int blk = blockIdx.y;
  const __bf16* Bblk = Bt + (size_t)blk * 128 * K;
  int wave = tid >> 6, lane = tid & 63;
  int wm = (wave & 1) * 64, wn = (wave >> 1) * 64;
  floatx4 acc[4][4] = {};

  int ar0 = tid >> 2, ch0 = tid & 3;
  int ar1 = (tid + 256) >> 2, ch1 = (tid + 256) & 3;
  int fm = lane & 15, fg = lane >> 4;

  for (int k0 = 0; k0 < K; k0 += 32) {
    int4v av0, av1, bv0, bv1;
    if (AF32) {
      const float* Af = (const float*)Ap;
      union { int4v i; __bf16 h[8]; } u0, u1;
      int g0 = m0 + ar0, g1 = m0 + ar1;
      floatx4 p0a = {}, p0b = {}, p1a = {}, p1b = {};
      if (g0 < M) {
        const float* p = Af + (size_t)g0 * K + k0 + ch0 * 8;
        p0a = *(const floatx4*)p; p0b = *(const floatx4*)(p + 4);
      }
      if (g1 < M) {
        const float* p = Af + (size_t)g1 * K + k0 + ch1 * 8;
        p1a = *(const floatx4*)p; p1b = *(const floatx4*)(p + 4);
      }
#pragma unroll
      for (int q = 0; q < 4; q++) { u0.h[q] = (__bf16)p0a[q]; u0.h[q + 4] = (__bf16)p0b[q]; }
#pragma unroll
      for (int q = 0; q < 4; q++) { u1.h[q] = (__bf16)p1a[q]; u1.h[q + 4] = (__bf16)p1b[q]; }
      av0 = u0.i; av1 = u1.i;
    } else {
      const __bf16* Ab = (const __bf16*)Ap;
      int g0 = m0 + ar0, g1 = m0 + ar1;
      int4v z = {0, 0, 0, 0};
      av0 = (g0 < M) ? *(const int4v*)(Ab + (size_t)g0 * K + k0 + ch0 * 8) : z;
      av1 = (g1 < M) ? *(const int4v*)(Ab + (size_t)g1 * K + k0 + ch1 * 8) : z;
    }
    bv0 = *(const int4v*)(Bblk + (size_t)ar0 * K + k0 + ch0 * 8);
    bv1 = *(const int4v*)(Bblk + (size_t)ar1 * K + k0 + ch1 * 8);

    __syncthreads();
    *(int4v*)(sA + ar0 * 40 + ch0 * 8) = av0;
    *(int4v*)(sA + ar1 * 40 + ch1 * 8) = av1;
    *(int4v*)(sB + ar0 * 40 + ch0 * 8) = bv0;
    *(int4v*)(sB + ar1 * 40 + ch1 * 8) = bv1;
    __syncthreads();

    bf16x8 af[4], bf[4];
#pragma unroll
    for (int mt = 0; mt < 4; mt++)
      af[mt] = *(const bf16x8*)(sA + (wm + mt * 16 + fm) * 40 + fg * 8);
#pragma unroll
    for (int nt = 0; nt < 4; nt++)
      bf[nt] = *(const bf16x8*)(sB + (wn + nt * 16 + fm) * 40 + fg * 8);
#pragma unroll
    for (int mt = 0; mt < 4; mt++)
#pragma unroll
      for (int nt = 0; nt < 4; nt++)
        acc[mt][nt] = __builtin_amdgcn_mfma_f32_16x16x32_bf16(af[mt], bf[nt], acc[mt][nt], 0, 0, 0);
  }

  int colb = lane & 15, rbase = (lane >> 4) << 2;
  const float* bp = HASB ? (bias + blk * 128) : nullptr;
#pragma unroll
  for (int mt = 0; mt < 4; mt++)
#pragma unroll
    for (int r = 0; r < 4; r++) {
      int gm = m0 + wm + mt * 16 + rbase + r;
      if (gm >= M) continue;
#pragma unroll
      for (int nt = 0; nt < 4; nt++) {
        int gc = wn + nt * 16 + colb;
        float vv = acc[mt][nt][r];
        if (HASB) { vv += bp[gc]; vv = fmaxf(vv, 0.f); }
        if (blk == 0) {
          if (O0F32) ((float*)out0)[(size_t)gm * s0 + gc] = vv;
          else       ((__bf16*)out0)[(size_t)gm * s0 + gc] = (__bf16)vv;
        } else if (blk == 1) {
          out1[(size_t)gm * s1 + gc] = (__bf16)vv;
        } else {
          out2[(size_t)gm * s2 + gc] = (__bf16)vv;
        }
      }
    }
}

// ---------------- constc[c] = bf[c] + sum_k b2[k] * wf[k][c] ----------------
__global__ void k_const(const float* __restrict__ b2, const float* __restrict__ wf,
                        const float* __restrict__ bf, float* __restrict__ constc) {
  int c = threadIdx.x;
  if (c >= NCLS) return;
  float s = bf[c];
  for (int k = 0; k < 384; k++) s += b2[k] * wf[k * NCLS + c];
  constc[c] = s;
}

// ---------------- final: logits = concat(f0,f1,f2) @ wf + constc; log_softmax
__global__ __launch_bounds__(256) void k_final(
    const float* __restrict__ f0, const float* __restrict__ f1,
    const float* __restrict__ f2, const float* __restrict__ wf,
    const float* __restrict__ constc, float* __restrict__ out) {
  __shared__ float swf[384 * NCLS];
  int tid = threadIdx.x;
  for (int i = tid; i < 384 * NCLS; i += 256) swf[i] = wf[i];
  __syncthreads();
  int r = blockIdx.x * 16 + (tid >> 4);
  int c = tid & 15;
  if (r >= N_NODES) return;
  float l = constc[c];
  const float* p0 = f0 + (size_t)r * HW_;
  const float* p1 = f1 + (size_t)r * HW_;
  const float* p2 = f2 + (size_t)r * HW_;
  for (int k = 0; k < HW_; k++) l += p0[k] * swf[k * NCLS + c];
  for (int k = 0; k < HW_; k++) l += p1[k] * swf[(HW_ + k) * NCLS + c];
  for (int k = 0; k < HW_; k++) l += p2[k] * swf[(2 * HW_ + k) * NCLS + c];
  float m = l;
  for (int o = 8; o >= 1; o >>= 1) m = fmaxf(m, __shfl_xor(m, o, 16));
  float s = expf(l - m);
  for (int o = 8; o >= 1; o >>= 1) s += __shfl_xor(s, o, 16);
  out[(size_t)r * NCLS + c] = (l - m) - logf(s);
}

// ---------------- launch ----------------
extern "C" void kernel_launch(void* const* d_in, const int* in_sizes, int n_in,
                              void* d_out, int out_size, void* d_ws, size_t ws_size,
                              hipStream_t stream) {
  const float* x   = (const float*)d_in[0];
  const int*   adj = (const int*)d_in[1];
  const float* av  = (const float*)d_in[2];
  const float* w1  = (const float*)d_in[3];
  const float* b1  = (const float*)d_in[4];
  const float* w2  = (const float*)d_in[5];
  const float* b2  = (const float*)d_in[6];
  const float* wf  = (const float*)d_in[7];
  const float* bf  = (const float*)d_in[8];
  float* out = (float*)d_out;

  char* ws = (char*)d_ws;
  size_t off = 0;
  auto alloc = [&](size_t bytes) -> void* {
    off = (off + 255) & ~(size_t)255;
    void* p = ws + off;
    off += bytes;
    return p;
  };

  __bf16* a1b = (__bf16*)alloc((size_t)N_NODES * 384 * 2);
  __bf16* Ab  = (__bf16*)alloc((size_t)N_NODES * HW_ * 2);
  __bf16* Bb  = (__bf16*)alloc((size_t)N_NODES * HW_ * 2);
  __bf16* Cb  = (__bf16*)alloc((size_t)N_NODES * HW_ * 2);
  float* F0   = (float*)alloc((size_t)N_NODES * HW_ * 4);
  float* F1   = (float*)alloc((size_t)N_NODES * HW_ * 4);
  float* F2   = (float*)alloc((size_t)N_NODES * HW_ * 4);
  __bf16* w1t = (__bf16*)alloc((size_t)3 * 128 * FIN * 2);
  __bf16* w2t = (__bf16*)alloc((size_t)3 * 128 * 384 * 2);
  int* rowptr = (int*)alloc((size_t)(N_NODES + 1) * 4);
  int* wcur   = (int*)alloc((size_t)N_NODES * 4);
  int* cnt    = (int*)alloc((size_t)N_NODES * 4);
  int* bsum   = (int*)alloc((size_t)SCAN_NB * 4);
  int* bsumex = (int*)alloc((size_t)SCAN_NB * 4);
  int2* epack = (int2*)alloc((size_t)N_EDGES * 8);
  float* cc   = (float*)alloc(64);

  // CSR build (parallel scan)
  hipMemsetAsync(cnt, 0, (size_t)N_NODES * 4, stream);
  k_hist<<<(N_EDGES + 255) / 256, 256, 0, stream>>>(adj, cnt);
  k_scan_block<<<SCAN_NB, 256, 0, stream>>>(cnt, bsum);
  k_scan_top<<<1, 256, 0, stream>>>(bsum, bsumex);
  k_scan_fill<<<SCAN_NB, 256, 0, stream>>>(cnt, bsumex, rowptr, wcur);
  k_scatter<<<(N_EDGES + 255) / 256, 256, 0, stream>>>(adj, av, wcur, epack);
  k_const<<<1, 64, 0, stream>>>(b2, wf, bf, cc);

  k_wt<<<(3 * FIN * 128 + 255) / 256, 256, 0, stream>>>(w1, w1t, FIN);
  k_wt<<<(3 * 384 * 128 + 255) / 256, 256, 0, stream>>>(w2, w2t, 384);

  dim3 g1((N_NODES + 127) / 128, 3);
  int spmm_grid = (N_NODES + 3) / 4;

  // GEMM1: relu(x@w1+b1): blk0 -> a1b cols 0-127 (bf16); blk1 -> Ab; blk2 -> Bb
  gemm_mfma<true, true, false><<<g1, 256, 0, stream>>>(
      (const void*)x, N_NODES, FIN, w1t, b1, (void*)a1b, 384, Ab, HW_, Bb, HW_);
  // upper hops (all bf16)
  spmm_csr<false><<<spmm_grid, 256, 0, stream>>>(rowptr, epack, Ab, (void*)(a1b + 128), 384);
  spmm_csr<false><<<spmm_grid, 256, 0, stream>>>(rowptr, epack, Bb, (void*)Ab, HW_);
  spmm_csr<false><<<spmm_grid, 256, 0, stream>>>(rowptr, epack, Ab, (void*)(a1b + 256), 384);

  // GEMM2: a1b@w2 (bias folded into constc): blk0 -> F0 (fp32); blk1 -> Bb; blk2 -> Cb
  gemm_mfma<false, false, true><<<g1, 256, 0, stream>>>(
      (const void*)a1b, N_NODES, 384, w2t, nullptr, (void*)F0, HW_, Bb, HW_, Cb, HW_);
  // bottom hops
  spmm_csr<true><<<spmm_grid, 256, 0, stream>>>(rowptr, epack, Bb, (void*)F1, HW_);
  spmm_csr<false><<<spmm_grid, 256, 0, stream>>>(rowptr, epack, Cb, (void*)Bb, HW_);
  spmm_csr<true><<<spmm_grid, 256, 0, stream>>>(rowptr, epack, Bb, (void*)F2, HW_);

  // final fused GEMM + log_softmax
  k_final<<<(N_NODES + 15) / 16, 256, 0, stream>>>(F0, F1, F2, wf, cc, out);
}